// Round 1
// baseline (642.926 us; speedup 1.0000x reference)
//
#include <hip/hip_runtime.h>
#include <hip/hip_bf16.h>
#include <stdint.h>

typedef __attribute__((ext_vector_type(8))) short s16x8;    // bf16 MFMA A/B frag (4 VGPRs)
typedef __attribute__((ext_vector_type(4))) float f32x4;    // MFMA C/D frag
typedef __attribute__((ext_vector_type(8))) unsigned short us8;
typedef __attribute__((ext_vector_type(4))) unsigned short us4;

// ---- bf16 round-to-nearest-even (inputs are finite normals) ----
__device__ inline unsigned short bf_rne(float f) {
    union { float f; uint32_t u; } v; v.f = f;
    uint32_t u = v.u;
    u += 0x7FFFu + ((u >> 16) & 1u);
    return (unsigned short)(u >> 16);
}

// async global->LDS, 16B per lane; LDS dst is wave-uniform base + lane*16
#define GLD_LDS16(gp, lp)                                                     \
    __builtin_amdgcn_global_load_lds(                                         \
        (const __attribute__((address_space(1))) void*)(gp),                  \
        (__attribute__((address_space(3))) void*)(lp), 16, 0, 0)

// ---------------- Kernel 1: x fp32 -> bf16 ----------------
// 33,554,432 elems; 8 per thread; 16384 blocks x 256
__global__ void cvt_x_kernel(const float4* __restrict__ x4,
                             unsigned short* __restrict__ xbf) {
    size_t t = (size_t)blockIdx.x * 256 + threadIdx.x;
    float4 a = x4[2 * t];
    float4 b = x4[2 * t + 1];
    us8 o;
    o[0] = bf_rne(a.x); o[1] = bf_rne(a.y); o[2] = bf_rne(a.z); o[3] = bf_rne(a.w);
    o[4] = bf_rne(b.x); o[5] = bf_rne(b.y); o[6] = bf_rne(b.z); o[7] = bf_rne(b.w);
    *(us8*)&xbf[t * 8] = o;
}

// ---------------- Kernel 2: adapted = W + B@A (bf16) + scale = mag/rownorm ----------------
// one block per output row m (4096 blocks x 256 threads)
__global__ void prep_w_kernel(const float4* __restrict__ W4,
                              const float4* __restrict__ A4,   // [16][1024] float4
                              const float* __restrict__ B,     // [4096][16]
                              const float* __restrict__ mag,   // [4096]
                              unsigned short* __restrict__ wbf,
                              float* __restrict__ scale) {
    const int m = blockIdx.x;
    const int tid = threadIdx.x;
    __shared__ float Bs[16];
    __shared__ float red[4];
    if (tid < 16) Bs[tid] = B[m * 16 + tid];
    __syncthreads();

    float ss = 0.f;
    for (int c = tid; c < 1024; c += 256) {
        float4 w = W4[(size_t)m * 1024 + c];
#pragma unroll
        for (int r = 0; r < 16; ++r) {
            float4 a = A4[r * 1024 + c];
            float br = Bs[r];
            w.x += br * a.x; w.y += br * a.y; w.z += br * a.z; w.w += br * a.w;
        }
        ss += w.x * w.x + w.y * w.y + w.z * w.z + w.w * w.w;
        us4 o; o[0] = bf_rne(w.x); o[1] = bf_rne(w.y); o[2] = bf_rne(w.z); o[3] = bf_rne(w.w);
        *(us4*)&wbf[(size_t)m * 4096 + c * 4] = o;
    }
    // wave reduce (64 lanes) then cross-wave via LDS
#pragma unroll
    for (int off = 32; off > 0; off >>= 1) ss += __shfl_down(ss, off, 64);
    const int lane = tid & 63, w = tid >> 6;
    if (lane == 0) red[w] = ss;
    __syncthreads();
    if (tid == 0) {
        float tot = red[0] + red[1] + red[2] + red[3];
        scale[m] = mag[m] / sqrtf(tot);
    }
}

// ---------------- Kernel 3: C[8192][4096] = xbf @ wbf^T * scale ----------------
// 128x128 tile, BK=64, 4 waves in 2x2, each wave 64x64 via 4x4 mfma_f32_16x16x32_bf16
__global__ __launch_bounds__(256) void dora_gemm(
    const unsigned short* __restrict__ xbf,   // [8192][4096] bf16
    const unsigned short* __restrict__ wbf,   // [4096][4096] bf16
    const float* __restrict__ scale,          // [4096]
    float* __restrict__ out) {                // [8192][4096] fp32
    __shared__ __align__(16) unsigned short As[128 * 64];
    __shared__ __align__(16) unsigned short Bs[128 * 64];

    const int tid  = threadIdx.x;
    const int lane = tid & 63;
    const int w    = tid >> 6;     // wave 0..3
    const int wm   = w >> 1;       // 0..1
    const int wn   = w & 1;        // 0..1
    const int tileM = (blockIdx.x >> 5) * 128;   // 64 M-tiles
    const int tileN = (blockIdx.x & 31) * 128;   // 32 N-tiles

    // staging geometry: per issue, lane i fills LDS 16B slot i of a 1024B group
    // group g covers rows g*8..g*8+7; lane i -> row g*8+(i>>3), phys chunk (i&7)
    // XOR swizzle: physical chunk p of row holds logical chunk p ^ (row&7)
    const int i8 = lane >> 3;                  // 0..7 (row within group)
    const int lc = (lane & 7) ^ i8;            // logical 16B chunk to fetch

    f32x4 acc[4][4] = {};

    for (int k0 = 0; k0 < 4096; k0 += 64) {
        __syncthreads();   // prior reads done before overwrite
#pragma unroll
        for (int j = 0; j < 4; ++j) {
            const int g   = w * 4 + j;         // 0..15
            const int row = g * 8 + i8;        // 0..127
            GLD_LDS16(xbf + (size_t)(tileM + row) * 4096 + k0 + lc * 8, &As[g * 512]);
            GLD_LDS16(wbf + (size_t)(tileN + row) * 4096 + k0 + lc * 8, &Bs[g * 512]);
        }
        __syncthreads();   // staging visible (vmcnt(0) drain at barrier)

        const int q   = lane >> 4;   // 0..3
        const int c15 = lane & 15;
#pragma unroll
        for (int kc = 0; kc < 2; ++kc) {
            s16x8 af[4], bfr[4];
#pragma unroll
            for (int mt = 0; mt < 4; ++mt) {
                const int row  = wm * 64 + mt * 16 + c15;
                const int phys = (kc * 4 + q) ^ (row & 7);
                af[mt] = *(const s16x8*)&As[row * 64 + phys * 8];
            }
#pragma unroll
            for (int nt = 0; nt < 4; ++nt) {
                const int row  = wn * 64 + nt * 16 + c15;
                const int phys = (kc * 4 + q) ^ (row & 7);
                bfr[nt] = *(const s16x8*)&Bs[row * 64 + phys * 8];
            }
#pragma unroll
            for (int mt = 0; mt < 4; ++mt)
#pragma unroll
                for (int nt = 0; nt < 4; ++nt)
                    acc[mt][nt] = __builtin_amdgcn_mfma_f32_16x16x32_bf16(
                        af[mt], bfr[nt], acc[mt][nt], 0, 0, 0);
        }
    }

    // epilogue: C/D layout col=lane&15, row=(lane>>4)*4+reg ; scale by mag/norm
    const int q   = lane >> 4;
    const int c15 = lane & 15;
#pragma unroll
    for (int nt = 0; nt < 4; ++nt) {
        const int col = tileN + wn * 64 + nt * 16 + c15;
        const float s = scale[col];
#pragma unroll
        for (int mt = 0; mt < 4; ++mt) {
            const int row0 = tileM + wm * 64 + mt * 16 + q * 4;
#pragma unroll
            for (int r = 0; r < 4; ++r)
                out[(size_t)(row0 + r) * 4096 + col] = acc[mt][nt][r] * s;
        }
    }
}

extern "C" void kernel_launch(void* const* d_in, const int* in_sizes, int n_in,
                              void* d_out, int out_size, void* d_ws, size_t ws_size,
                              hipStream_t stream) {
    const float* x   = (const float*)d_in[0];   // [4,2048,4096]
    const float* W   = (const float*)d_in[1];   // [4096,4096]
    const float* A   = (const float*)d_in[2];   // [16,4096]
    const float* B   = (const float*)d_in[3];   // [4096,16]
    const float* mag = (const float*)d_in[4];   // [4096]
    float* out = (float*)d_out;

    const size_t XBF_BYTES = (size_t)8192 * 4096 * 2;  // 67,108,864
    const size_t WBF_BYTES = (size_t)4096 * 4096 * 2;  // 33,554,432
    const size_t NEEDED = XBF_BYTES + WBF_BYTES + 4096 * sizeof(float);
    if (ws_size < NEEDED) return;  // visible failure -> restructure next round

    unsigned short* xbf = (unsigned short*)d_ws;
    unsigned short* wbf = (unsigned short*)((char*)d_ws + XBF_BYTES);
    float* scale = (float*)((char*)d_ws + XBF_BYTES + WBF_BYTES);

    cvt_x_kernel<<<16384, 256, 0, stream>>>((const float4*)x, xbf);
    prep_w_kernel<<<4096, 256, 0, stream>>>((const float4*)W, (const float4*)A,
                                            B, mag, wbf, scale);
    dora_gemm<<<2048, 256, 0, stream>>>(xbf, wbf, scale, out);
}